// Round 7
// baseline (159.144 us; speedup 1.0000x reference)
//
#include <hip/hip_runtime.h>
#include <hip/hip_bf16.h>

typedef __attribute__((ext_vector_type(8))) short bf16x8;
typedef __attribute__((ext_vector_type(4))) short bf16x4;
typedef __attribute__((ext_vector_type(4))) float f32x4;

__device__ __forceinline__ void gload_lds16(const void* g, void* l) {
    __builtin_amdgcn_global_load_lds(
        (const __attribute__((address_space(1))) unsigned int*)g,
        (__attribute__((address_space(3))) unsigned int*)l, 16, 0, 0);
}

// 16x16x16 bf16 MFMA (HW-verified in round 6)
__device__ __forceinline__ f32x4 mfma_16x16x16(bf16x4 a, bf16x4 b, f32x4 c) {
#if __has_builtin(__builtin_amdgcn_mfma_f32_16x16x16bf16_1k)
    return __builtin_amdgcn_mfma_f32_16x16x16bf16_1k(a, b, c, 0, 0, 0);
#else
    f32x4 d = c;
    asm volatile("v_mfma_f32_16x16x16_bf16 %0, %1, %2, %0" : "+v"(d) : "v"(a), "v"(b));
    return d;
#endif
}

// ---------------- fp32 -> bf16 elementwise convert (8 elems/thread) ----------------
__global__ void k_cvt_bf16(const float* __restrict__ x, __hip_bfloat16* __restrict__ o, int n8) {
    int i = blockIdx.x * 256 + threadIdx.x;
    if (i >= n8) return;
    const float4* xp = (const float4*)(x + (size_t)i * 8);
    float4 a = xp[0], b = xp[1];
    union { __hip_bfloat16 h[8]; uint4 u; } tu;
    tu.h[0] = __float2bfloat16(a.x); tu.h[1] = __float2bfloat16(a.y);
    tu.h[2] = __float2bfloat16(a.z); tu.h[3] = __float2bfloat16(a.w);
    tu.h[4] = __float2bfloat16(b.x); tu.h[5] = __float2bfloat16(b.y);
    tu.h[6] = __float2bfloat16(b.z); tu.h[7] = __float2bfloat16(b.w);
    *(uint4*)(o + (size_t)i * 8) = tu.u;
}

// ---------------- transpose fp32 [K][N] -> bf16 [N][K]; z selects one of 3 sources ----------------
__global__ void k_tr3(const float* __restrict__ s0, const float* __restrict__ s1,
                      const float* __restrict__ s2, __hip_bfloat16* __restrict__ dst,
                      int K, int N) {
    __shared__ float tile[32][33];
    const float* src = (blockIdx.z == 0) ? s0 : ((blockIdx.z == 1) ? s1 : s2);
    __hip_bfloat16* d = dst + (size_t)blockIdx.z * N * K;
    int n0 = blockIdx.x * 32, k0 = blockIdx.y * 32;
    int tx = threadIdx.x & 31, ty = threadIdx.x >> 5;
#pragma unroll
    for (int i = 0; i < 4; i++)
        tile[ty + i * 8][tx] = src[(size_t)(k0 + ty + i * 8) * N + n0 + tx];
    __syncthreads();
#pragma unroll
    for (int i = 0; i < 4; i++)
        d[(size_t)(n0 + ty + i * 8) * K + k0 + tx] = __float2bfloat16(tile[tx][ty + i * 8]);
}

__global__ void k_tr(const float* __restrict__ src, __hip_bfloat16* __restrict__ dst, int K, int N) {
    __shared__ float tile[32][33];
    int n0 = blockIdx.x * 32, k0 = blockIdx.y * 32;
    int tx = threadIdx.x & 31, ty = threadIdx.x >> 5;
#pragma unroll
    for (int i = 0; i < 4; i++)
        tile[ty + i * 8][tx] = src[(size_t)(k0 + ty + i * 8) * N + n0 + tx];
    __syncthreads();
#pragma unroll
    for (int i = 0; i < 4; i++)
        dst[(size_t)(n0 + ty + i * 8) * K + k0 + tx] = __float2bfloat16(tile[tx][ty + i * 8]);
}

// ---------------- bf16 GEMM (round-3 proven, natural 2D grid, NO swizzle) ----------------
#define QSCALE 0.18033688011111204f  /* (1/8) * log2(e) */

template <int EPI>
__global__ __launch_bounds__(256, 2) void k_gemm(
    const __hip_bfloat16* __restrict__ A, const __hip_bfloat16* __restrict__ Bt,
    int M, int N, int K,
    const float* __restrict__ b0, const float* __restrict__ b1, const float* __restrict__ b2,
    __hip_bfloat16* __restrict__ qb, __hip_bfloat16* __restrict__ kb, __hip_bfloat16* __restrict__ vb,
    float* __restrict__ outp)
{
    __shared__ __align__(16) __hip_bfloat16 As[128 * 64];
    __shared__ __align__(16) __hip_bfloat16 Bs[128 * 64];
    const int t = threadIdx.x;
    const int lane = t & 63, w = t >> 6;
    const int wr = w >> 1, wc = w & 1;
    const int r16 = lane & 15, kg = lane >> 4;
    const int m0 = blockIdx.x * 128, n0 = blockIdx.y * 128;
    f32x4 acc[4][4] = {};
    const int ksteps = K >> 6;
    for (int kt = 0; kt < ksteps; ++kt) {
        if (kt) __syncthreads();
        const int ks = kt * 64;
#pragma unroll
        for (int i = 0; i < 4; i++) {
            int ci = i * 256 + t;
            int row = ci >> 3, kc = (ci & 7) * 8;
            gload_lds16(A + (size_t)(m0 + row) * K + ks + kc, As + ci * 8);
        }
#pragma unroll
        for (int i = 0; i < 4; i++) {
            int ci = i * 256 + t;
            int row = ci >> 3, kc = (ci & 7) * 8;
            gload_lds16(Bt + (size_t)(n0 + row) * K + ks + kc, Bs + ci * 8);
        }
        __syncthreads();
#pragma unroll
        for (int c = 0; c < 2; c++) {
            bf16x8 af[4], bfr[4];
#pragma unroll
            for (int mi = 0; mi < 4; mi++)
                af[mi] = *(const bf16x8*)(As + (wr * 64 + mi * 16 + r16) * 64 + c * 32 + kg * 8);
#pragma unroll
            for (int ni = 0; ni < 4; ni++)
                bfr[ni] = *(const bf16x8*)(Bs + (wc * 64 + ni * 16 + r16) * 64 + c * 32 + kg * 8);
#pragma unroll
            for (int mi = 0; mi < 4; mi++)
#pragma unroll
                for (int ni = 0; ni < 4; ni++)
                    acc[mi][ni] = __builtin_amdgcn_mfma_f32_16x16x32_bf16(af[mi], bfr[ni], acc[mi][ni], 0, 0, 0);
        }
    }
#pragma unroll
    for (int mi = 0; mi < 4; mi++) {
#pragma unroll
        for (int ni = 0; ni < 4; ni++) {
#pragma unroll
            for (int j = 0; j < 4; j++) {
                int m = m0 + wr * 64 + mi * 16 + kg * 4 + j;
                int n = n0 + wc * 64 + ni * 16 + r16;
                float val = acc[mi][ni][j];
                if (EPI == 0) {
                    int proj = n >> 10, r = n & 1023;
                    int hh = r >> 6, dd = r & 63;
                    int bb = m >> 11, tt = m & 2047;
                    if (proj == 0) {
                        val = (val + b0[r]) * QSCALE;
                        qb[((size_t)(bb * 16 + hh) * 2048 + tt) * 64 + dd] = __float2bfloat16(val);
                    } else if (proj == 1) {
                        val += b1[r];
                        kb[((size_t)(bb * 16 + hh) * 2048 + tt) * 64 + dd] = __float2bfloat16(val);
                    } else {
                        val += b2[r];
                        vb[((size_t)(bb * 16 + hh) * 64 + dd) * 2048 + tt] = __float2bfloat16(val);
                    }
                } else {
                    outp[(size_t)m * N + n] = val + b0[n];
                }
            }
        }
    }
}

// ---------------- flash attention v7: v6 core + KVBLK=128 (half the barriers) ----------------
// Per-iter compute (~1400 cyc: 16 x32 QK + 32 exp2 + 32 x16 PV) now covers the ~900-cyc
// prefetch latency that the drain-barrier re-exposed every 64-k iteration in v3/v6.
// Geometry: 16 q-rows/wave, 64 q-rows/block, 1024 blocks; LDS 64KB -> 2 blocks/CU.
// Invariant: kbase = kt*128 <= (qt>>1)*128 <= qt*64 <= q0  (no fully-masked q-rows).
__global__ __launch_bounds__(256, 2) void k_attn(
    const __hip_bfloat16* __restrict__ qbuf,
    const __hip_bfloat16* __restrict__ kbuf,
    const __hip_bfloat16* __restrict__ vtbuf,
    __hip_bfloat16* __restrict__ y)
{
    __shared__ __align__(16) __hip_bfloat16 Kl[2][128 * 64];
    __shared__ __align__(16) __hip_bfloat16 Vl[2][64 * 128];
    const int t = threadIdx.x, lane = t & 63, w = t >> 6;
    const int r16 = lane & 15, kg = lane >> 4;
    // balanced remap: co-resident {g, g+256, g+512, g+768} have qt sum = 62
    const int g = blockIdx.x;
    const int c4 = g >> 8, p = g & 255;
    const int bh = (p >> 5) * 4 + c4;
    const int rr = p & 31;
    const int qt = (c4 & 1) ? rr : 31 - rr;
    const int nt = (qt >> 1) + 1;          // 128-wide KV tiles
    const int swr = (r16 & 7) << 3;        // read-side XOR swizzle (elements)
    const int q0 = qt * 64 + w * 16;       // wave's q base
    const __hip_bfloat16* qp = qbuf + ((size_t)bh * 2048 + q0) * 64;
    bf16x8 qf0 = *(const bf16x8*)(qp + r16 * 64 + kg * 8);
    bf16x8 qf1 = *(const bf16x8*)(qp + r16 * 64 + 32 + kg * 8);
    f32x4 O[4] = {};                 // O[ot]: q=kg*4+j, d=ot*16+r16
    float m_s = -3.0e38f, l_s = 0.f; // per-lane state for q = r16
    const __hip_bfloat16* kb = kbuf + (size_t)bh * 2048 * 64;
    const __hip_bfloat16* vb = vtbuf + (size_t)bh * 64 * 2048;

    // staging indices: K tile [128 rows][64 cols] (4 chunks), V^T tile [64 rows][128 cols] (4 chunks)
    // pre-swizzled global source, linear LDS dest (XOR is an involution; read applies same XOR)
    int kroww[4], kcoll[4], vroww[4], vcoll[4];
#pragma unroll
    for (int c = 0; c < 4; c++) {
        const int ci = c * 256 + t;
        kroww[c] = ci >> 3; kcoll[c] = ((ci & 7) * 8) ^ ((kroww[c] & 7) << 3);
        vroww[c] = ci >> 4; vcoll[c] = ((ci & 15) * 8) ^ ((vroww[c] & 7) << 3);
    }

    auto stage = [&](int buf, int kt) {
#pragma unroll
        for (int c = 0; c < 4; c++) {
            const int ci = c * 256 + t;
            gload_lds16(kb + ((size_t)kt * 128 + kroww[c]) * 64 + kcoll[c], &Kl[buf][ci * 8]);
        }
#pragma unroll
        for (int c = 0; c < 4; c++) {
            const int ci = c * 256 + t;
            gload_lds16(vb + (size_t)vroww[c] * 2048 + kt * 128 + vcoll[c], &Vl[buf][ci * 8]);
        }
    };

    stage(0, 0);
    __syncthreads();

    for (int kt = 0; kt < nt; ++kt) {
        const int cur = kt & 1;
        if (kt + 1 < nt) stage(cur ^ 1, kt + 1);  // latency hides under this tile's compute
        const int kbase = kt * 128;
        {
            const __hip_bfloat16* Klb = Kl[cur];
            const __hip_bfloat16* Vlb = Vl[cur];
            // swapped QK^T: S[ct]: lane holds S[k=ct*16+kg*4+j][q=r16], ct = 0..7
            f32x4 S[8];
            __builtin_amdgcn_s_setprio(1);
#pragma unroll
            for (int ct = 0; ct < 8; ct++) {
                f32x4 s = {};
                const int r = ct * 16 + r16;
                bf16x8 kf0 = *(const bf16x8*)(Klb + r * 64 + ((kg * 8) ^ swr));
                s = __builtin_amdgcn_mfma_f32_16x16x32_bf16(kf0, qf0, s, 0, 0, 0);
                bf16x8 kf1 = *(const bf16x8*)(Klb + r * 64 + ((32 + kg * 8) ^ swr));
                s = __builtin_amdgcn_mfma_f32_16x16x32_bf16(kf1, qf1, s, 0, 0, 0);
                S[ct] = s;
            }
            __builtin_amdgcn_s_setprio(0);
            if (kbase + 127 > q0) {  // causal mask on partial tiles
#pragma unroll
                for (int ct = 0; ct < 8; ct++)
#pragma unroll
                    for (int j = 0; j < 4; j++)
                        if (kbase + ct * 16 + kg * 4 + j > q0 + r16) S[ct][j] = -3.0e38f;
            }
            float rmax = S[0][0];
#pragma unroll
            for (int ct = 0; ct < 8; ct++)
#pragma unroll
                for (int j = 0; j < 4; j++) rmax = fmaxf(rmax, S[ct][j]);
            rmax = fmaxf(rmax, __shfl_xor(rmax, 16));
            rmax = fmaxf(rmax, __shfl_xor(rmax, 32));
            // defer-max (T13, THR=8)
            if (__any(rmax > m_s + 8.0f)) {
                const float mn = fmaxf(m_s, rmax);
                const float al = exp2f(m_s - mn);
                m_s = mn;
                l_s *= al;
#pragma unroll
                for (int j = 0; j < 4; j++) {
                    const float aj = __shfl(al, kg * 4 + j);
#pragma unroll
                    for (int ot = 0; ot < 4; ot++) O[ot][j] *= aj;
                }
            }
            float rsum = 0.f;
#pragma unroll
            for (int ct = 0; ct < 8; ct++)
#pragma unroll
                for (int j = 0; j < 4; j++) { S[ct][j] = exp2f(S[ct][j] - m_s); rsum += S[ct][j]; }
            rsum += __shfl_xor(rsum, 16);
            rsum += __shfl_xor(rsum, 32);
            l_s += rsum;
            // pack P quads (zero cross-lane movement; QK C-layout == x16 A-layout)
            bf16x4 pa[8];
#pragma unroll
            for (int ct = 0; ct < 8; ct++) {
                union { __hip_bfloat16 h[4]; bf16x4 v; } pk;
                pk.h[0] = __float2bfloat16(S[ct][0]);
                pk.h[1] = __float2bfloat16(S[ct][1]);
                pk.h[2] = __float2bfloat16(S[ct][2]);
                pk.h[3] = __float2bfloat16(S[ct][3]);
                pa[ct] = pk.v;
            }
            __builtin_amdgcn_s_setprio(1);
#pragma unroll
            for (int ot = 0; ot < 4; ot++) {
                const int vrow = ot * 16 + r16;   // V^T row = d
#pragma unroll
                for (int ct = 0; ct < 8; ct++) {
                    bf16x4 vf = *(const bf16x4*)(Vlb + vrow * 128 + ((ct * 16 + kg * 4) ^ swr));
                    O[ot] = mfma_16x16x16(pa[ct], vf, O[ot]);
                }
            }
            __builtin_amdgcn_s_setprio(0);
        }
        __syncthreads();  // drain: next buffer staged; cur buffer free to overwrite
    }
    const int b = bh >> 4, h = bh & 15;
    const float linv = 1.0f / l_s;
#pragma unroll
    for (int j = 0; j < 4; j++) {
        const float iv = __shfl(linv, kg * 4 + j);
        const int qq = q0 + kg * 4 + j;
#pragma unroll
        for (int ot = 0; ot < 4; ot++)
            y[((size_t)b * 2048 + qq) * 1024 + h * 64 + ot * 16 + r16] = __float2bfloat16(O[ot][j] * iv);
    }
}

extern "C" void kernel_launch(void* const* d_in, const int* in_sizes, int n_in,
                              void* d_out, int out_size, void* d_ws, size_t ws_size,
                              hipStream_t stream) {
    const float* xp = (const float*)d_in[0];
    const float* Wq = (const float*)d_in[1];
    const float* bq = (const float*)d_in[2];
    const float* Wk = (const float*)d_in[3];
    const float* bk = (const float*)d_in[4];
    const float* Wv = (const float*)d_in[5];
    const float* bv = (const float*)d_in[6];
    const float* Wp = (const float*)d_in[7];
    const float* bp = (const float*)d_in[8];
    float* out = (float*)d_out;

    char* ws = (char*)d_ws;
    __hip_bfloat16* xb     = (__hip_bfloat16*)(ws);                  //  4096*1152 bf16
    __hip_bfloat16* Wqkv_t = (__hip_bfloat16*)(ws + 9437184);        //  3072*1152 bf16 (B^T)
    __hip_bfloat16* Wp_t   = (__hip_bfloat16*)(ws + 16515072);       //  1024*1024 bf16 (B^T)
    __hip_bfloat16* qb     = (__hip_bfloat16*)(ws + 18612224);       //  [32][2048][64]
    __hip_bfloat16* kbv    = (__hip_bfloat16*)(ws + 27000832);       //  [32][2048][64]
    __hip_bfloat16* vtb    = (__hip_bfloat16*)(ws + 35389440);       //  [32][64][2048] (V^T)
    __hip_bfloat16* yb     = (__hip_bfloat16*)(ws + 43778048);       //  [4096][1024]

    k_cvt_bf16<<<2304, 256, 0, stream>>>(xp, xb, 589824);
    dim3 trg3(1024 / 32, 1152 / 32, 3);
    k_tr3<<<trg3, 256, 0, stream>>>(Wq, Wk, Wv, Wqkv_t, 1152, 1024);
    dim3 trg2(1024 / 32, 1024 / 32);
    k_tr<<<trg2, 256, 0, stream>>>(Wp, Wp_t, 1024, 1024);

    dim3 g1(4096 / 128, 3072 / 128);
    k_gemm<0><<<g1, 256, 0, stream>>>(xb, Wqkv_t, 4096, 3072, 1152, bq, bk, bv, qb, kbv, vtb, nullptr);
    k_attn<<<1024, 256, 0, stream>>>(qb, kbv, vtb, yb);
    dim3 g2(4096 / 128, 1024 / 128);
    k_gemm<1><<<g2, 256, 0, stream>>>(yb, Wp_t, 4096, 1024, 1024, bp, nullptr, nullptr,
                                      nullptr, nullptr, nullptr, out);
}

// Round 8
// 154.084 us; speedup vs baseline: 1.0328x; 1.0328x over previous
//
#include <hip/hip_runtime.h>
#include <hip/hip_bf16.h>

typedef __attribute__((ext_vector_type(8))) short bf16x8;
typedef __attribute__((ext_vector_type(4))) float f32x4;
typedef __attribute__((ext_vector_type(16))) float f32x16;

__device__ __forceinline__ void gload_lds16(const void* g, void* l) {
    __builtin_amdgcn_global_load_lds(
        (const __attribute__((address_space(1))) unsigned int*)g,
        (__attribute__((address_space(3))) unsigned int*)l, 16, 0, 0);
}

__device__ __forceinline__ unsigned int pk2(float x, float y) {
    union { __hip_bfloat16 h[2]; unsigned int u; } z;
    z.h[0] = __float2bfloat16(x); z.h[1] = __float2bfloat16(y);
    return z.u;
}

// ---------------- fp32 -> bf16 elementwise convert (8 elems/thread) ----------------
__global__ void k_cvt_bf16(const float* __restrict__ x, __hip_bfloat16* __restrict__ o, int n8) {
    int i = blockIdx.x * 256 + threadIdx.x;
    if (i >= n8) return;
    const float4* xp = (const float4*)(x + (size_t)i * 8);
    float4 a = xp[0], b = xp[1];
    union { __hip_bfloat16 h[8]; uint4 u; } tu;
    tu.h[0] = __float2bfloat16(a.x); tu.h[1] = __float2bfloat16(a.y);
    tu.h[2] = __float2bfloat16(a.z); tu.h[3] = __float2bfloat16(a.w);
    tu.h[4] = __float2bfloat16(b.x); tu.h[5] = __float2bfloat16(b.y);
    tu.h[6] = __float2bfloat16(b.z); tu.h[7] = __float2bfloat16(b.w);
    *(uint4*)(o + (size_t)i * 8) = tu.u;
}

// ---------------- transpose fp32 [K][N] -> bf16 [N][K]; z selects one of 3 sources ----------------
__global__ void k_tr3(const float* __restrict__ s0, const float* __restrict__ s1,
                      const float* __restrict__ s2, __hip_bfloat16* __restrict__ dst,
                      int K, int N) {
    __shared__ float tile[32][33];
    const float* src = (blockIdx.z == 0) ? s0 : ((blockIdx.z == 1) ? s1 : s2);
    __hip_bfloat16* d = dst + (size_t)blockIdx.z * N * K;
    int n0 = blockIdx.x * 32, k0 = blockIdx.y * 32;
    int tx = threadIdx.x & 31, ty = threadIdx.x >> 5;
#pragma unroll
    for (int i = 0; i < 4; i++)
        tile[ty + i * 8][tx] = src[(size_t)(k0 + ty + i * 8) * N + n0 + tx];
    __syncthreads();
#pragma unroll
    for (int i = 0; i < 4; i++)
        d[(size_t)(n0 + ty + i * 8) * K + k0 + tx] = __float2bfloat16(tile[tx][ty + i * 8]);
}

__global__ void k_tr(const float* __restrict__ src, __hip_bfloat16* __restrict__ dst, int K, int N) {
    __shared__ float tile[32][33];
    int n0 = blockIdx.x * 32, k0 = blockIdx.y * 32;
    int tx = threadIdx.x & 31, ty = threadIdx.x >> 5;
#pragma unroll
    for (int i = 0; i < 4; i++)
        tile[ty + i * 8][tx] = src[(size_t)(k0 + ty + i * 8) * N + n0 + tx];
    __syncthreads();
#pragma unroll
    for (int i = 0; i < 4; i++)
        dst[(size_t)(n0 + ty + i * 8) * K + k0 + tx] = __float2bfloat16(tile[tx][ty + i * 8]);
}

// ---------------- bf16 GEMM (round-3 proven, natural 2D grid) ----------------
#define QSCALE 0.18033688011111204f  /* (1/8) * log2(e) */

template <int EPI>
__global__ __launch_bounds__(256, 2) void k_gemm(
    const __hip_bfloat16* __restrict__ A, const __hip_bfloat16* __restrict__ Bt,
    int M, int N, int K,
    const float* __restrict__ b0, const float* __restrict__ b1, const float* __restrict__ b2,
    __hip_bfloat16* __restrict__ qb, __hip_bfloat16* __restrict__ kb, __hip_bfloat16* __restrict__ vb,
    float* __restrict__ outp)
{
    __shared__ __align__(16) __hip_bfloat16 As[128 * 64];
    __shared__ __align__(16) __hip_bfloat16 Bs[128 * 64];
    const int t = threadIdx.x;
    const int lane = t & 63, w = t >> 6;
    const int wr = w >> 1, wc = w & 1;
    const int r16 = lane & 15, kg = lane >> 4;
    const int m0 = blockIdx.x * 128, n0 = blockIdx.y * 128;
    f32x4 acc[4][4] = {};
    const int ksteps = K >> 6;
    for (int kt = 0; kt < ksteps; ++kt) {
        if (kt) __syncthreads();
        const int ks = kt * 64;
#pragma unroll
        for (int i = 0; i < 4; i++) {
            int ci = i * 256 + t;
            int row = ci >> 3, kc = (ci & 7) * 8;
            gload_lds16(A + (size_t)(m0 + row) * K + ks + kc, As + ci * 8);
        }
#pragma unroll
        for (int i = 0; i < 4; i++) {
            int ci = i * 256 + t;
            int row = ci >> 3, kc = (ci & 7) * 8;
            gload_lds16(Bt + (size_t)(n0 + row) * K + ks + kc, Bs + ci * 8);
        }
        __syncthreads();
#pragma unroll
        for (int c = 0; c < 2; c++) {
            bf16x8 af[4], bfr[4];
#pragma unroll
            for (int mi = 0; mi < 4; mi++)
                af[mi] = *(const bf16x8*)(As + (wr * 64 + mi * 16 + r16) * 64 + c * 32 + kg * 8);
#pragma unroll
            for (int ni = 0; ni < 4; ni++)
                bfr[ni] = *(const bf16x8*)(Bs + (wc * 64 + ni * 16 + r16) * 64 + c * 32 + kg * 8);
#pragma unroll
            for (int mi = 0; mi < 4; mi++)
#pragma unroll
                for (int ni = 0; ni < 4; ni++)
                    acc[mi][ni] = __builtin_amdgcn_mfma_f32_16x16x32_bf16(af[mi], bfr[ni], acc[mi][ni], 0, 0, 0);
        }
    }
#pragma unroll
    for (int mi = 0; mi < 4; mi++) {
#pragma unroll
        for (int ni = 0; ni < 4; ni++) {
#pragma unroll
            for (int j = 0; j < 4; j++) {
                int m = m0 + wr * 64 + mi * 16 + kg * 4 + j;
                int n = n0 + wc * 64 + ni * 16 + r16;
                float val = acc[mi][ni][j];
                if (EPI == 0) {
                    int proj = n >> 10, r = n & 1023;
                    int hh = r >> 6, dd = r & 63;
                    int bb = m >> 11, tt = m & 2047;
                    if (proj == 0) {
                        val = (val + b0[r]) * QSCALE;
                        qb[((size_t)(bb * 16 + hh) * 2048 + tt) * 64 + dd] = __float2bfloat16(val);
                    } else if (proj == 1) {
                        val += b1[r];
                        kb[((size_t)(bb * 16 + hh) * 2048 + tt) * 64 + dd] = __float2bfloat16(val);
                    } else {
                        val += b2[r];
                        vb[((size_t)(bb * 16 + hh) * 64 + dd) * 2048 + tt] = __float2bfloat16(val);
                    }
                } else {
                    outp[(size_t)m * N + n] = val + b0[n];
                }
            }
        }
    }
}

// ---------------- flash attention v8: 32-q-row waves in 2-wave/64-row blocks ----------------
// v4's verified 32x32 swapped-QK core (in-register P via pack+shfl_xor(32)) at v6's
// occupancy geometry: grid 1024, 32 KB LDS -> 4 blocks/CU. Halves wave-tile count
// (33.8k vs 67.6k) and reduce/shfl chains per output vs 16-row waves.
// + pairwise-tree rmax/rsum (serial chain 32 -> ~5 deep), T5 setprio on MFMA clusters.
__global__ __launch_bounds__(128, 2) void k_attn(
    const __hip_bfloat16* __restrict__ qbuf,
    const __hip_bfloat16* __restrict__ kbuf,
    const __hip_bfloat16* __restrict__ vtbuf,
    __hip_bfloat16* __restrict__ y)
{
    __shared__ __align__(16) __hip_bfloat16 Kl[2][64 * 64];
    __shared__ __align__(16) __hip_bfloat16 Vl[2][64 * 64];
    const int t = threadIdx.x, lane = t & 63, w = t >> 6;  // w in {0,1}
    const int l31 = lane & 31, hi = lane >> 5;
    // balanced remap (round-3 proven): co-resident {g, g+256, g+512, g+768} have qt-sum 62
    const int g = blockIdx.x;
    const int c4 = g >> 8, p = g & 255;
    const int bh = (p >> 5) * 4 + c4;
    const int rr = p & 31;
    const int qt = (c4 & 1) ? rr : 31 - rr;
    const int nt = qt + 1;                 // 64-wide KV tiles
    const int q0w = qt * 64 + w * 32;      // wave's 32-row q base
    const int swr = (l31 & 7) << 3;        // read-side XOR swizzle (elements)

    const __hip_bfloat16* qp = qbuf + ((size_t)bh * 2048 + q0w + l31) * 64;
    bf16x8 qf[4];
#pragma unroll
    for (int dt = 0; dt < 4; dt++)
        qf[dt] = *(const bf16x8*)(qp + dt * 16 + hi * 8);

    f32x16 O0 = {}, O1 = {};
    float m_s = -3.0e38f, l_s = 0.f;
    const __hip_bfloat16* kb = kbuf + (size_t)bh * 2048 * 64;
    const __hip_bfloat16* vb = vtbuf + (size_t)bh * 64 * 2048;

    // staging: 8 chunks x 128 threads x 16B cover K(8KB)+V(8KB); pre-swizzled source
    int krw[4], scl[4];
#pragma unroll
    for (int c = 0; c < 4; c++) {
        const int ci = c * 128 + t;
        krw[c] = ci >> 3;
        scl[c] = ((ci & 7) * 8) ^ ((krw[c] & 7) << 3);
    }

    auto stage = [&](int buf, int kt) {
#pragma unroll
        for (int c = 0; c < 4; c++)
            gload_lds16(kb + ((size_t)kt * 64 + krw[c]) * 64 + scl[c], &Kl[buf][(c * 128 + t) * 8]);
#pragma unroll
        for (int c = 0; c < 4; c++)
            gload_lds16(vb + (size_t)krw[c] * 2048 + kt * 64 + scl[c], &Vl[buf][(c * 128 + t) * 8]);
    };

    stage(0, 0);
    __syncthreads();

    for (int kt = 0; kt < nt; ++kt) {
        const int cur = kt & 1;
        if (kt + 1 < nt) stage(cur ^ 1, kt + 1);  // latency hides under this tile's compute
        const int kbase = kt * 64;
        if (kbase <= q0w + 31) {  // wave-uniform activity gate
            const __hip_bfloat16* Klb = Kl[cur];
            const __hip_bfloat16* Vlb = Vl[cur];
            // swapped QK^T: lane holds S^T[k][q=l31]; k rows = (r&3)+8*(r>>2)+4*hi (+32 for s1)
            f32x16 s0 = {}, s1 = {};
            __builtin_amdgcn_s_setprio(1);
#pragma unroll
            for (int dt = 0; dt < 4; dt++) {
                bf16x8 ka = *(const bf16x8*)(Klb + l31 * 64 + ((dt * 16 + hi * 8) ^ swr));
                s0 = __builtin_amdgcn_mfma_f32_32x32x16_bf16(ka, qf[dt], s0, 0, 0, 0);
            }
#pragma unroll
            for (int dt = 0; dt < 4; dt++) {
                bf16x8 kb2 = *(const bf16x8*)(Klb + (32 + l31) * 64 + ((dt * 16 + hi * 8) ^ swr));
                s1 = __builtin_amdgcn_mfma_f32_32x32x16_bf16(kb2, qf[dt], s1, 0, 0, 0);
            }
            __builtin_amdgcn_s_setprio(0);
            if (kbase + 63 > q0w) {  // causal mask (partial-overlap tiles only)
                const int qg = q0w + l31;
#pragma unroll
                for (int r = 0; r < 16; ++r) {
                    const int krow = (r & 3) + 8 * (r >> 2) + 4 * hi;
                    if (kbase + krow > qg) s0[r] = -3.0e38f;
                    if (kbase + 32 + krow > qg) s1[r] = -3.0e38f;
                }
            }
            // tree row-max (depth ~5 instead of 32-deep chain)
            float a[16];
#pragma unroll
            for (int r = 0; r < 16; ++r) a[r] = fmaxf(s0[r], s1[r]);
#pragma unroll
            for (int s = 8; s > 0; s >>= 1)
#pragma unroll
                for (int r = 0; r < s; ++r) a[r] = fmaxf(a[r], a[r + s]);
            float rmax = fmaxf(a[0], __shfl_xor(a[0], 32));
            // defer-max (T13, THR=8)
            if (__any(rmax > m_s + 8.0f)) {
                const float mn = fmaxf(m_s, rmax);
                const float al = exp2f(m_s - mn);
                m_s = mn;
                l_s *= al;
#pragma unroll
                for (int r = 0; r < 16; ++r) {
                    const int qrow = (r & 3) + 8 * (r >> 2) + 4 * hi;
                    const float ar = __shfl(al, qrow);
                    O0[r] *= ar; O1[r] *= ar;
                }
            }
#pragma unroll
            for (int r = 0; r < 16; ++r) { s0[r] = exp2f(s0[r] - m_s); s1[r] = exp2f(s1[r] - m_s); }
            // tree row-sum
            float b2[16];
#pragma unroll
            for (int r = 0; r < 16; ++r) b2[r] = s0[r] + s1[r];
#pragma unroll
            for (int s = 8; s > 0; s >>= 1)
#pragma unroll
                for (int r = 0; r < s; ++r) b2[r] += b2[r + s];
            l_s += b2[0] + __shfl_xor(b2[0], 32);
            // P -> PV A-frags fully in-register (pack pairs, exchange halves via shfl_xor 32)
            bf16x8 pa[4];
#pragma unroll
            for (int kt4 = 0; kt4 < 4; ++kt4) {
                const f32x16& sc = (kt4 < 2) ? s0 : s1;
                const int a8 = (kt4 & 1) * 8;
                const unsigned int plo0 = pk2(sc[a8 + 0], sc[a8 + 1]);
                const unsigned int plo1 = pk2(sc[a8 + 2], sc[a8 + 3]);
                const unsigned int phi0 = pk2(sc[a8 + 4], sc[a8 + 5]);
                const unsigned int phi1 = pk2(sc[a8 + 6], sc[a8 + 7]);
                const unsigned int snd0 = hi ? plo0 : phi0;
                const unsigned int snd1 = hi ? plo1 : phi1;
                const unsigned int r0 = (unsigned int)__shfl_xor((int)snd0, 32);
                const unsigned int r1 = (unsigned int)__shfl_xor((int)snd1, 32);
                union { unsigned int u[4]; bf16x8 v; } fr;
                fr.u[0] = hi ? r0 : plo0;
                fr.u[1] = hi ? r1 : plo1;
                fr.u[2] = hi ? phi0 : r0;
                fr.u[3] = hi ? phi1 : r1;
                pa[kt4] = fr.v;
            }
            __builtin_amdgcn_s_setprio(1);
#pragma unroll
            for (int kt4 = 0; kt4 < 4; ++kt4) {
                bf16x8 vf0 = *(const bf16x8*)(Vlb + l31 * 64 + ((kt4 * 16 + hi * 8) ^ swr));
                O0 = __builtin_amdgcn_mfma_f32_32x32x16_bf16(pa[kt4], vf0, O0, 0, 0, 0);
                bf16x8 vf1 = *(const bf16x8*)(Vlb + (32 + l31) * 64 + ((kt4 * 16 + hi * 8) ^ swr));
                O1 = __builtin_amdgcn_mfma_f32_32x32x16_bf16(pa[kt4], vf1, O1, 0, 0, 0);
            }
            __builtin_amdgcn_s_setprio(0);
        }
        __syncthreads();  // drain: next buffer staged; cur buffer free
    }
    const int b = bh >> 4, h = bh & 15;
    const float linv = 1.0f / l_s;
#pragma unroll
    for (int r = 0; r < 16; ++r) {
        const int qrow = (r & 3) + 8 * (r >> 2) + 4 * hi;
        const float iv = __shfl(linv, qrow);
        const size_t ro = ((size_t)b * 2048 + q0w + qrow) * 1024 + (size_t)h * 64;
        y[ro + l31] = __float2bfloat16(O0[r] * iv);
        y[ro + 32 + l31] = __float2bfloat16(O1[r] * iv);
    }
}

extern "C" void kernel_launch(void* const* d_in, const int* in_sizes, int n_in,
                              void* d_out, int out_size, void* d_ws, size_t ws_size,
                              hipStream_t stream) {
    const float* xp = (const float*)d_in[0];
    const float* Wq = (const float*)d_in[1];
    const float* bq = (const float*)d_in[2];
    const float* Wk = (const float*)d_in[3];
    const float* bk = (const float*)d_in[4];
    const float* Wv = (const float*)d_in[5];
    const float* bv = (const float*)d_in[6];
    const float* Wp = (const float*)d_in[7];
    const float* bp = (const float*)d_in[8];
    float* out = (float*)d_out;

    char* ws = (char*)d_ws;
    __hip_bfloat16* xb     = (__hip_bfloat16*)(ws);                  //  4096*1152 bf16
    __hip_bfloat16* Wqkv_t = (__hip_bfloat16*)(ws + 9437184);        //  3072*1152 bf16 (B^T)
    __hip_bfloat16* Wp_t   = (__hip_bfloat16*)(ws + 16515072);       //  1024*1024 bf16 (B^T)
    __hip_bfloat16* qb     = (__hip_bfloat16*)(ws + 18612224);       //  [32][2048][64]
    __hip_bfloat16* kbv    = (__hip_bfloat16*)(ws + 27000832);       //  [32][2048][64]
    __hip_bfloat16* vtb    = (__hip_bfloat16*)(ws + 35389440);       //  [32][64][2048] (V^T)
    __hip_bfloat16* yb     = (__hip_bfloat16*)(ws + 43778048);       //  [4096][1024]

    k_cvt_bf16<<<2304, 256, 0, stream>>>(xp, xb, 589824);
    dim3 trg3(1024 / 32, 1152 / 32, 3);
    k_tr3<<<trg3, 256, 0, stream>>>(Wq, Wk, Wv, Wqkv_t, 1152, 1024);
    dim3 trg2(1024 / 32, 1024 / 32);
    k_tr<<<trg2, 256, 0, stream>>>(Wp, Wp_t, 1024, 1024);

    dim3 g1(4096 / 128, 3072 / 128);
    k_gemm<0><<<g1, 256, 0, stream>>>(xb, Wqkv_t, 4096, 3072, 1152, bq, bk, bv, qb, kbv, vtb, nullptr);
    k_attn<<<1024, 128, 0, stream>>>(qb, kbv, vtb, yb);
    dim3 g2(4096 / 128, 1024 / 128);
    k_gemm<1><<<g2, 256, 0, stream>>>(yb, Wp_t, 4096, 1024, 1024, bp, nullptr, nullptr,
                                      nullptr, nullptr, nullptr, out);
}

// Round 9
// 137.256 us; speedup vs baseline: 1.1595x; 1.1226x over previous
//
#include <hip/hip_runtime.h>
#include <hip/hip_bf16.h>

typedef __attribute__((ext_vector_type(8))) short bf16x8;
typedef __attribute__((ext_vector_type(4))) short bf16x4;
typedef __attribute__((ext_vector_type(4))) float f32x4;
typedef __attribute__((ext_vector_type(2))) unsigned int u32x2;

__device__ __forceinline__ void gload_lds16(const void* g, void* l) {
    __builtin_amdgcn_global_load_lds(
        (const __attribute__((address_space(1))) unsigned int*)g,
        (__attribute__((address_space(3))) unsigned int*)l, 16, 0, 0);
}

__device__ __forceinline__ unsigned int pk2(float x, float y) {
    union { __hip_bfloat16 h[2]; unsigned int u; } z;
    z.h[0] = __float2bfloat16(x); z.h[1] = __float2bfloat16(y);
    return z.u;
}

// 16x16x16 bf16 MFMA (HW-verified round 6)
__device__ __forceinline__ f32x4 mfma_16x16x16(bf16x4 a, bf16x4 b, f32x4 c) {
#if __has_builtin(__builtin_amdgcn_mfma_f32_16x16x16bf16_1k)
    return __builtin_amdgcn_mfma_f32_16x16x16bf16_1k(a, b, c, 0, 0, 0);
#else
    f32x4 d = c;
    asm volatile("v_mfma_f32_16x16x16_bf16 %0, %1, %2, %0" : "+v"(d) : "v"(a), "v"(b));
    return d;
#endif
}

// ---------------- fp32 -> bf16 elementwise convert (8 elems/thread) ----------------
__global__ void k_cvt_bf16(const float* __restrict__ x, __hip_bfloat16* __restrict__ o, int n8) {
    int i = blockIdx.x * 256 + threadIdx.x;
    if (i >= n8) return;
    const float4* xp = (const float4*)(x + (size_t)i * 8);
    float4 a = xp[0], b = xp[1];
    union { __hip_bfloat16 h[8]; uint4 u; } tu;
    tu.h[0] = __float2bfloat16(a.x); tu.h[1] = __float2bfloat16(a.y);
    tu.h[2] = __float2bfloat16(a.z); tu.h[3] = __float2bfloat16(a.w);
    tu.h[4] = __float2bfloat16(b.x); tu.h[5] = __float2bfloat16(b.y);
    tu.h[6] = __float2bfloat16(b.z); tu.h[7] = __float2bfloat16(b.w);
    *(uint4*)(o + (size_t)i * 8) = tu.u;
}

// ---------------- transpose fp32 [K][N] -> bf16 [N][K]; z selects one of 3 sources ----------------
__global__ void k_tr3(const float* __restrict__ s0, const float* __restrict__ s1,
                      const float* __restrict__ s2, __hip_bfloat16* __restrict__ dst,
                      int K, int N) {
    __shared__ float tile[32][33];
    const float* src = (blockIdx.z == 0) ? s0 : ((blockIdx.z == 1) ? s1 : s2);
    __hip_bfloat16* d = dst + (size_t)blockIdx.z * N * K;
    int n0 = blockIdx.x * 32, k0 = blockIdx.y * 32;
    int tx = threadIdx.x & 31, ty = threadIdx.x >> 5;
#pragma unroll
    for (int i = 0; i < 4; i++)
        tile[ty + i * 8][tx] = src[(size_t)(k0 + ty + i * 8) * N + n0 + tx];
    __syncthreads();
#pragma unroll
    for (int i = 0; i < 4; i++)
        d[(size_t)(n0 + ty + i * 8) * K + k0 + tx] = __float2bfloat16(tile[tx][ty + i * 8]);
}

__global__ void k_tr(const float* __restrict__ src, __hip_bfloat16* __restrict__ dst, int K, int N) {
    __shared__ float tile[32][33];
    int n0 = blockIdx.x * 32, k0 = blockIdx.y * 32;
    int tx = threadIdx.x & 31, ty = threadIdx.x >> 5;
#pragma unroll
    for (int i = 0; i < 4; i++)
        tile[ty + i * 8][tx] = src[(size_t)(k0 + ty + i * 8) * N + n0 + tx];
    __syncthreads();
#pragma unroll
    for (int i = 0; i < 4; i++)
        dst[(size_t)(n0 + ty + i * 8) * K + k0 + tx] = __float2bfloat16(tile[tx][ty + i * 8]);
}

// ---------------- bf16 GEMM (round-3 proven core) + V-epilogue LDS transpose ----------------
// V^T scatter was 64 x 2B stores/thread at 4KB lane stride. New path (n0>=2048, EPI=0):
// reuse the dead As/Bs 32KB as a [128n][128m] bf16 tile (XOR-swizzled), ds_write_b64 packed
// quads, barrier, then 8 x (ds_read_b128 + 16B coalesced global store) per thread.
#define QSCALE 0.18033688011111204f  /* (1/8) * log2(e) */

template <int EPI>
__global__ __launch_bounds__(256, 2) void k_gemm(
    const __hip_bfloat16* __restrict__ A, const __hip_bfloat16* __restrict__ Bt,
    int M, int N, int K,
    const float* __restrict__ b0, const float* __restrict__ b1, const float* __restrict__ b2,
    __hip_bfloat16* __restrict__ qb, __hip_bfloat16* __restrict__ kb, __hip_bfloat16* __restrict__ vb,
    float* __restrict__ outp)
{
    __shared__ __align__(16) __hip_bfloat16 Sh[16384];  // As = Sh[0:8192], Bs = Sh[8192:]
    __hip_bfloat16* As = Sh;
    __hip_bfloat16* Bs = Sh + 8192;
    const int t = threadIdx.x;
    const int lane = t & 63, w = t >> 6;
    const int wr = w >> 1, wc = w & 1;
    const int r16 = lane & 15, kg = lane >> 4;
    const int m0 = blockIdx.x * 128, n0 = blockIdx.y * 128;
    f32x4 acc[4][4] = {};
    const int ksteps = K >> 6;
    for (int kt = 0; kt < ksteps; ++kt) {
        if (kt) __syncthreads();
        const int ks = kt * 64;
#pragma unroll
        for (int i = 0; i < 4; i++) {
            int ci = i * 256 + t;
            int row = ci >> 3, kc = (ci & 7) * 8;
            gload_lds16(A + (size_t)(m0 + row) * K + ks + kc, As + ci * 8);
        }
#pragma unroll
        for (int i = 0; i < 4; i++) {
            int ci = i * 256 + t;
            int row = ci >> 3, kc = (ci & 7) * 8;
            gload_lds16(Bt + (size_t)(n0 + row) * K + ks + kc, Bs + ci * 8);
        }
        __syncthreads();
#pragma unroll
        for (int c = 0; c < 2; c++) {
            bf16x8 af[4], bfr[4];
#pragma unroll
            for (int mi = 0; mi < 4; mi++)
                af[mi] = *(const bf16x8*)(As + (wr * 64 + mi * 16 + r16) * 64 + c * 32 + kg * 8);
#pragma unroll
            for (int ni = 0; ni < 4; ni++)
                bfr[ni] = *(const bf16x8*)(Bs + (wc * 64 + ni * 16 + r16) * 64 + c * 32 + kg * 8);
#pragma unroll
            for (int mi = 0; mi < 4; mi++)
#pragma unroll
                for (int ni = 0; ni < 4; ni++)
                    acc[mi][ni] = __builtin_amdgcn_mfma_f32_16x16x32_bf16(af[mi], bfr[ni], acc[mi][ni], 0, 0, 0);
        }
    }
    if (EPI == 0 && n0 >= 2048) {
        // ---- V path: transpose through LDS, coalesced 16B stores ----
        __syncthreads();  // all waves done reading As/Bs
#pragma unroll
        for (int mi = 0; mi < 4; mi++) {
#pragma unroll
            for (int ni = 0; ni < 4; ni++) {
                const int nl = wc * 64 + ni * 16 + r16;           // local n (0..127)
                const int mb = wr * 64 + mi * 16 + kg * 4;        // local m base (mult of 4)
                const int r = n0 - 2048 + nl;                     // 0..1023 within V
                const float bias = b2[r];
                u32x2 pk;
                pk[0] = pk2(acc[mi][ni][0] + bias, acc[mi][ni][1] + bias);
                pk[1] = pk2(acc[mi][ni][2] + bias, acc[mi][ni][3] + bias);
                *(u32x2*)(Sh + nl * 128 + (mb ^ ((nl & 7) << 3))) = pk;
            }
        }
        __syncthreads();
#pragma unroll
        for (int pass = 0; pass < 8; ++pass) {
            const int ci = pass * 256 + t;
            const int nl = ci >> 4;            // 0..127
            const int ms = (ci & 15) * 8;      // 0..120
            bf16x8 v = *(const bf16x8*)(Sh + nl * 128 + (ms ^ ((nl & 7) << 3)));
            const int r = n0 - 2048 + nl;
            const int hh = r >> 6, dd = r & 63;
            const int m = m0 + ms;
            const int bb = m >> 11, tt = m & 2047;
            *(bf16x8*)(vb + ((size_t)(bb * 16 + hh) * 64 + dd) * 2048 + tt) = v;
        }
        return;
    }
#pragma unroll
    for (int mi = 0; mi < 4; mi++) {
#pragma unroll
        for (int ni = 0; ni < 4; ni++) {
#pragma unroll
            for (int j = 0; j < 4; j++) {
                int m = m0 + wr * 64 + mi * 16 + kg * 4 + j;
                int n = n0 + wc * 64 + ni * 16 + r16;
                float val = acc[mi][ni][j];
                if (EPI == 0) {
                    int r = n & 1023;
                    int hh = r >> 6, dd = r & 63;
                    int bb = m >> 11, tt = m & 2047;
                    if (n < 1024) {
                        val = (val + b0[r]) * QSCALE;
                        qb[((size_t)(bb * 16 + hh) * 2048 + tt) * 64 + dd] = __float2bfloat16(val);
                    } else {
                        val += b1[r];
                        kb[((size_t)(bb * 16 + hh) * 2048 + tt) * 64 + dd] = __float2bfloat16(val);
                    }
                } else {
                    outp[(size_t)m * N + n] = val + b0[n];
                }
            }
        }
    }
}

// ---------------- flash attention v6 (proven ~57us): 16x16 swapped QK + in-register P ----------------
__global__ __launch_bounds__(256, 4) void k_attn(
    const __hip_bfloat16* __restrict__ qbuf,
    const __hip_bfloat16* __restrict__ kbuf,
    const __hip_bfloat16* __restrict__ vtbuf,
    __hip_bfloat16* __restrict__ y)
{
    __shared__ __align__(16) __hip_bfloat16 Kl[2][64 * 64];
    __shared__ __align__(16) __hip_bfloat16 Vl[2][64 * 64];
    const int t = threadIdx.x, lane = t & 63, w = t >> 6;
    const int r16 = lane & 15, kg = lane >> 4;
    // balanced remap: co-resident {g, g+256, g+512, g+768} have qt sum = 62
    const int g = blockIdx.x;
    const int c4 = g >> 8, p = g & 255;
    const int bh = (p >> 5) * 4 + c4;
    const int rr = p & 31;
    const int qt = (c4 & 1) ? rr : 31 - rr;
    const int swr = (r16 & 7) << 3;  // read-side XOR swizzle (elements)
    const int q0 = qt * 64 + w * 16;  // wave's q base
    const __hip_bfloat16* qp = qbuf + ((size_t)bh * 2048 + q0) * 64;
    bf16x8 qf0 = *(const bf16x8*)(qp + r16 * 64 + kg * 8);
    bf16x8 qf1 = *(const bf16x8*)(qp + r16 * 64 + 32 + kg * 8);
    f32x4 O[4] = {};                 // O[ot]: q=kg*4+j, d=ot*16+r16
    float m_s = -3.0e38f, l_s = 0.f; // per-lane state for q = r16 (4 kg copies)
    const __hip_bfloat16* kb = kbuf + (size_t)bh * 2048 * 64;
    const __hip_bfloat16* vb = vtbuf + (size_t)bh * 64 * 2048;

    const int ci0 = t, ci1 = 256 + t;
    const int kr0 = ci0 >> 3, sc0 = ((ci0 & 7) * 8) ^ ((kr0 & 7) << 3);
    const int kr1 = ci1 >> 3, sc1 = ((ci1 & 7) * 8) ^ ((kr1 & 7) << 3);

    // prologue: stage tile 0 into buffer 0 (pre-swizzled global source, linear LDS dest)
    gload_lds16(kb + (size_t)kr0 * 64 + sc0, &Kl[0][ci0 * 8]);
    gload_lds16(kb + (size_t)kr1 * 64 + sc1, &Kl[0][ci1 * 8]);
    gload_lds16(vb + (size_t)kr0 * 2048 + sc0, &Vl[0][ci0 * 8]);
    gload_lds16(vb + (size_t)kr1 * 2048 + sc1, &Vl[0][ci1 * 8]);
    __syncthreads();

    for (int kt = 0; kt <= qt; ++kt) {
        const int cur = kt & 1;
        if (kt < qt) {  // prefetch next tile; latency hides under this tile's compute
            const int kn = kt + 1;
            gload_lds16(kb + (size_t)kn * 4096 + (size_t)kr0 * 64 + sc0, &Kl[cur ^ 1][ci0 * 8]);
            gload_lds16(kb + (size_t)kn * 4096 + (size_t)kr1 * 64 + sc1, &Kl[cur ^ 1][ci1 * 8]);
            gload_lds16(vb + (size_t)kr0 * 2048 + kn * 64 + sc0, &Vl[cur ^ 1][ci0 * 8]);
            gload_lds16(vb + (size_t)kr1 * 2048 + kn * 64 + sc1, &Vl[cur ^ 1][ci1 * 8]);
        }
        const int kbase = kt * 64;
        if (kbase <= q0 + 15) {  // wave-uniform activity gate
            const __hip_bfloat16* Klb = Kl[cur];
            const __hip_bfloat16* Vlb = Vl[cur];
            // swapped QK^T: S[ct]: lane holds S[k=ct*16+kg*4+j][q=r16]
            f32x4 S[4];
            __builtin_amdgcn_s_setprio(1);
#pragma unroll
            for (int ct = 0; ct < 4; ct++) {
                f32x4 s = {};
                const int r = ct * 16 + r16;
                bf16x8 kf0 = *(const bf16x8*)(Klb + r * 64 + ((kg * 8) ^ swr));
                s = __builtin_amdgcn_mfma_f32_16x16x32_bf16(kf0, qf0, s, 0, 0, 0);
                bf16x8 kf1 = *(const bf16x8*)(Klb + r * 64 + ((32 + kg * 8) ^ swr));
                s = __builtin_amdgcn_mfma_f32_16x16x32_bf16(kf1, qf1, s, 0, 0, 0);
                S[ct] = s;
            }
            __builtin_amdgcn_s_setprio(0);
            if (kbase + 63 > q0) {  // causal mask on partial tiles; k = kbase+ct*16+kg*4+j, q = q0+r16
#pragma unroll
                for (int ct = 0; ct < 4; ct++)
#pragma unroll
                    for (int j = 0; j < 4; j++)
                        if (kbase + ct * 16 + kg * 4 + j > q0 + r16) S[ct][j] = -3.0e38f;
            }
            float rmax = S[0][0];
#pragma unroll
            for (int ct = 0; ct < 4; ct++)
#pragma unroll
                for (int j = 0; j < 4; j++) rmax = fmaxf(rmax, S[ct][j]);
            rmax = fmaxf(rmax, __shfl_xor(rmax, 16));
            rmax = fmaxf(rmax, __shfl_xor(rmax, 32));
            // defer-max (T13, THR=8)
            if (__any(rmax > m_s + 8.0f)) {
                const float mn = fmaxf(m_s, rmax);
                const float al = exp2f(m_s - mn);
                m_s = mn;
                l_s *= al;
#pragma unroll
                for (int j = 0; j < 4; j++) {
                    const float aj = __shfl(al, kg * 4 + j);  // state for q=kg*4+j lives in lane kg*4+j
#pragma unroll
                    for (int ot = 0; ot < 4; ot++) O[ot][j] *= aj;
                }
            }
            float rsum = 0.f;
#pragma unroll
            for (int ct = 0; ct < 4; ct++)
#pragma unroll
                for (int j = 0; j < 4; j++) { S[ct][j] = exp2f(S[ct][j] - m_s); rsum += S[ct][j]; }
            rsum += __shfl_xor(rsum, 16);
            rsum += __shfl_xor(rsum, 32);
            l_s += rsum;
            // pack P quads (zero cross-lane movement) and run PV with x16 MFMAs
            bf16x4 pa[4];
#pragma unroll
            for (int ct = 0; ct < 4; ct++) {
                union { __hip_bfloat16 h[4]; bf16x4 v; } pk;
                pk.h[0] = __float2bfloat16(S[ct][0]);
                pk.h[1] = __float2bfloat16(S[ct][1]);
                pk.h[2] = __float2bfloat16(S[ct][2]);
                pk.h[3] = __float2bfloat16(S[ct][3]);
                pa[ct] = pk.v;
            }
            __builtin_amdgcn_s_setprio(1);
#pragma unroll
            for (int ot = 0; ot < 4; ot++) {
                const int vrow = ot * 16 + r16;   // V^T row = d
#pragma unroll
                for (int ct = 0; ct < 4; ct++) {
                    // B-frag: V[k][d], k = ct*16 + kg*4 + e (4 consecutive, 8B read)
                    bf16x4 vf = *(const bf16x4*)(Vlb + vrow * 64 + ((ct * 16 + kg * 4) ^ ((vrow & 7) << 3)));
                    O[ot] = mfma_16x16x16(pa[ct], vf, O[ot]);
                }
            }
            __builtin_amdgcn_s_setprio(0);
        }
        __syncthreads();  // drain: next buffer staged; cur buffer free to overwrite
    }
    const int b = bh >> 4, h = bh & 15;
    const float linv = 1.0f / l_s;
#pragma unroll
    for (int j = 0; j < 4; j++) {
        const float iv = __shfl(linv, kg * 4 + j);
        const int qq = q0 + kg * 4 + j;
#pragma unroll
        for (int ot = 0; ot < 4; ot++)
            y[((size_t)b * 2048 + qq) * 1024 + h * 64 + ot * 16 + r16] = __float2bfloat16(O[ot][j] * iv);
    }
}

extern "C" void kernel_launch(void* const* d_in, const int* in_sizes, int n_in,
                              void* d_out, int out_size, void* d_ws, size_t ws_size,
                              hipStream_t stream) {
    const float* xp = (const float*)d_in[0];
    const float* Wq = (const float*)d_in[1];
    const float* bq = (const float*)d_in[2];
    const float* Wk = (const float*)d_in[3];
    const float* bk = (const float*)d_in[4];
    const float* Wv = (const float*)d_in[5];
    const float* bv = (const float*)d_in[6];
    const float* Wp = (const float*)d_in[7];
    const float* bp = (const float*)d_in[8];
    float* out = (float*)d_out;

    char* ws = (char*)d_ws;
    __hip_bfloat16* xb     = (__hip_bfloat16*)(ws);                  //  4096*1152 bf16
    __hip_bfloat16* Wqkv_t = (__hip_bfloat16*)(ws + 9437184);        //  3072*1152 bf16 (B^T)
    __hip_bfloat16* Wp_t   = (__hip_bfloat16*)(ws + 16515072);       //  1024*1024 bf16 (B^T)
    __hip_bfloat16* qb     = (__hip_bfloat16*)(ws + 18612224);       //  [32][2048][64]
    __hip_bfloat16* kbv    = (__hip_bfloat16*)(ws + 27000832);       //  [32][2048][64]
    __hip_bfloat16* vtb    = (__hip_bfloat16*)(ws + 35389440);       //  [32][64][2048] (V^T)
    __hip_bfloat16* yb     = (__hip_bfloat16*)(ws + 43778048);       //  [4096][1024]

    k_cvt_bf16<<<2304, 256, 0, stream>>>(xp, xb, 589824);
    dim3 trg3(1024 / 32, 1152 / 32, 3);
    k_tr3<<<trg3, 256, 0, stream>>>(Wq, Wk, Wv, Wqkv_t, 1152, 1024);
    dim3 trg2(1024 / 32, 1024 / 32);
    k_tr<<<trg2, 256, 0, stream>>>(Wp, Wp_t, 1024, 1024);

    dim3 g1(4096 / 128, 3072 / 128);
    k_gemm<0><<<g1, 256, 0, stream>>>(xb, Wqkv_t, 4096, 3072, 1152, bq, bk, bv, qb, kbv, vtb, nullptr);
    k_attn<<<1024, 256, 0, stream>>>(qb, kbv, vtb, yb);
    dim3 g2(4096 / 128, 1024 / 128);
    k_gemm<1><<<g2, 256, 0, stream>>>(yb, Wp_t, 4096, 1024, 1024, bp, nullptr, nullptr,
                                      nullptr, nullptr, nullptr, out);
}